// Round 13
// baseline (34.900 us; speedup 1.0000x reference)
//
#include <hip/hip_runtime.h>
#include <stdint.h>

#define NA   3
#define KCH  8       // 5 + NUM_CLASSES
#define BLK  512
#define NWV  (BLK / 64)
#define NB   2048    // stage-1 bins: key16 >> 5 (sign+8exp+2mant)
#define MAXN 19200   // 3 * 80 * 80
#define QCAP 512

#define LOG2E 1.4426950408889634f
#define LN2   0.6931471805599453f

struct ScaleParams {
  const float*   pred;    // (B, 24, H, W)
  const float*   boxes;   // (B, N, 4)
  const int*     labels;  // (B, N)
  const uint8_t* pos;     // (B, N) bool
  const uint8_t* neg;     // (B, N) bool
  int HW;
};

// ladder rungs: key16 of softplus(x) for x = 1.0, 1.5, 2.0, 2.5, 3.0.
// Values need not be exact — count >= k is verified at runtime.
__constant__ unsigned LADDER[5] = {0xBFA8u, 0xBFD9u, 0xC008u, 0xC025u, 0xC043u};

__device__ __forceinline__ float fexp2(float x) { return __builtin_amdgcn_exp2f(x); }
__device__ __forceinline__ float flog2(float x) { return __builtin_amdgcn_logf(x); }

// logaddexp(0,x) = max(x,0) + log1p(exp(-|x|)); native exp2/log2, ~1e-6 rel
__device__ __forceinline__ float softplus_fast(float x) {
  const float t = fexp2(-fabsf(x) * LOG2E);
  return fmaxf(x, 0.f) + flog2(1.f + t) * LN2;
}

__device__ __forceinline__ float sl1f(float d) {
  float ad = fabsf(d);
  return (ad < 1.f) ? 0.5f * d * d : ad - 0.5f;
}

// order-preserving float->uint key (larger float => larger key)
__device__ __forceinline__ unsigned fkey(unsigned u) {
  return (u & 0x80000000u) ? ~u : (u | 0x80000000u);
}
__device__ __forceinline__ unsigned funkey(unsigned k) {
  return (k & 0x80000000u) ? (k & 0x7FFFFFFFu) : ~k;
}

// reconstruct approx value from 16-bit key (midpoint of the key interval)
__device__ __forceinline__ float recon16(unsigned k16) {
  return __uint_as_float(funkey((k16 << 16) | 0x8000u));
}

__device__ __forceinline__ float blockSum(float v, float* scr) {
  #pragma unroll
  for (int off = 32; off > 0; off >>= 1) v += __shfl_down(v, off);
  const int lane = threadIdx.x & 63, w = threadIdx.x >> 6;
  __syncthreads();                       // protect scr reuse
  if (lane == 0) scr[w] = v;
  __syncthreads();
  float r = 0.f;
  #pragma unroll
  for (int i = 0; i < NWV; ++i) r += scr[i];   // same-address broadcast
  return r;
}

// Stage-1 select: per-thread 4 consecutive bins (counts only) of ascending-key
// hist; find bin holding the krem-th LARGEST and remaining count inside it.
__device__ __forceinline__ void selectBin1(const unsigned* cb, int krem_in,
    int* iwav, int* sh_dig, int* sh_krem) {
  const int t = threadIdx.x, lane = t & 63, w = t >> 6;
  const int c_t = (int)(cb[0] + cb[1] + cb[2] + cb[3]);
  int ci = c_t;                          // wave inclusive suffix scan
  #pragma unroll
  for (int off = 1; off < 64; off <<= 1) {
    const int co = __shfl_down(ci, off);
    if (lane + off < 64) ci += co;
  }
  __syncthreads();                       // protect iwav reuse
  if (lane == 0) iwav[w] = ci;
  __syncthreads();
  int ac = 0;
  #pragma unroll
  for (int w2 = 0; w2 < NWV; ++w2) if (w2 > w) ac += iwav[w2];
  int cum_c = (ci - c_t) + ac;           // count strictly above thread's top bin
  #pragma unroll
  for (int q = 3; q >= 0; --q) {
    const int cq = (int)cb[q];
    if (cq > 0 && cum_c < krem_in && krem_in <= cum_c + cq) {  // unique bracket
      *sh_dig  = t * 4 + q;
      *sh_krem = krem_in - cum_c;
    }
    cum_c += cq;
  }
  __syncthreads();
}

__global__ void k_zero(float* out, unsigned* done) {
  if (threadIdx.x < 4) out[threadIdx.x] = 0.f;
  if (threadIdx.x == 0) *done = 0u;
}

struct RowShared {
  unsigned short keys[MAXN];   // 38.4 KB (0 = not-neg)
  unsigned hc[NB];             // 8 KB
  int      queue[QCAP];
  int      sh_qn;
  int      iwav[NWV];
  float    fscr[NWV];
  float    wred[NWV][9];       // packed block reduction scratch
  int      sh_dig, sh_krem;
  float    sh_sa, sh_avg;
  unsigned c32[32];
  float    s32[32];
};

// Whole-row processing with compile-time N. Sweep 1: prefetch-all, keys->LDS,
// ladder counts in registers (NO histogram atomics). Ladder picks a prefilter
// threshold; sparse 2048-bin hist built from LDS keys (only ~3-7% atomics);
// 2-stage select as before.
template<int N>
__device__ __forceinline__ void row_impl(
    const ScaleParams P, int b, int R, float invB,
    float* out, unsigned* done, RowShared& S) {
  constexpr int HW = N / 3;
  constexpr int ITER = (N + BLK * 8 - 1) / (BLK * 8);
  const int t = threadIdx.x;

  for (int i = t; i < NB; i += BLK) S.hc[i] = 0u;
  if (t == 0) S.sh_qn = 0;
  __syncthreads();

  const float* predb = P.pred + (size_t)b * (NA * KCH) * HW;
  const size_t row = (size_t)b * N;
  float nneg = 0.f;
  int lad0 = 0, lad1 = 0, lad2 = 0, lad3 = 0, lad4 = 0;

  // ---- sweep 1, phase A: issue ALL global loads (compile-time unroll) ----
  float4 o0[ITER], o1[ITER];
  uint2  pmv[ITER], nmv[ITER];
  #pragma unroll
  for (int it = 0; it < ITER; ++it) {
    const int c8 = it * (BLK * 8) + t * 8;
    if (c8 < N) {
      const int a = (c8 >= HW) + (c8 >= 2 * HW);
      const int cell = c8 - a * HW;
      const float* po = predb + (size_t)a * KCH * HW + 4 * HW + cell;
      o0[it]  = *(const float4*)po;
      o1[it]  = *(const float4*)(po + 4);
      pmv[it] = *(const uint2*)(P.pos + row + c8);
      nmv[it] = *(const uint2*)(P.neg + row + c8);
    }
  }

  // ---- sweep 1, phase B: keys -> LDS, ladder counts, pos queue ----
  #pragma unroll
  for (int it = 0; it < ITER; ++it) {
    const int c8 = it * (BLK * 8) + t * 8;
    if (c8 < N) {
      unsigned kk[8];
      #pragma unroll
      for (int q = 0; q < 8; ++q) {
        const float obj = (q < 4) ? (&o0[it].x)[q] : (&o1[it].x)[q - 4];
        const unsigned nm = ((q < 4) ? (nmv[it].x >> (8 * q))
                                     : (nmv[it].y >> (8 * (q - 4)))) & 0xFFu;
        const unsigned pm = ((q < 4) ? (pmv[it].x >> (8 * q))
                                     : (pmv[it].y >> (8 * (q - 4)))) & 0xFFu;
        unsigned k16 = 0u;
        if (nm) {
          nneg += 1.f;
          k16 = fkey(__float_as_uint(obj)) >> 16;
          k16 = max(k16, 1u);                    // 0 reserved for "not neg"
        }
        kk[q] = k16;
        lad0 += (k16 > LADDER[0]); lad1 += (k16 > LADDER[1]);
        lad2 += (k16 > LADDER[2]); lad3 += (k16 > LADDER[3]);
        lad4 += (k16 > LADDER[4]);
        if (pm) {
          const int idx = atomicAdd(&S.sh_qn, 1);
          if (idx < QCAP) S.queue[idx] = c8 + q;
        }
      }
      uint4 kv;
      kv.x = kk[0] | (kk[1] << 16); kv.y = kk[2] | (kk[3] << 16);
      kv.z = kk[4] | (kk[5] << 16); kv.w = kk[6] | (kk[7] << 16);
      *reinterpret_cast<uint4*>(&S.keys[c8]) = kv;
    }
  }
  __syncthreads();
  const int npos = S.sh_qn;
  const int qn = min(npos, QCAP);

  // ---- dense pos-anchor work (~1%): softplus/CE/smooth-L1, L2-hot ----
  float posobj = 0.f, ce = 0.f, loc = 0.f;
  for (int i = t; i < qn; i += BLK) {
    const int j = S.queue[i];
    const int a = (j >= HW) + (j >= 2 * HW);
    const int cell = j - a * HW;
    const float* pa = predb + (size_t)a * KCH * HW;
    posobj += softplus_fast(-pa[4 * HW + cell]);     // sp(x)-x == sp(-x)
    const float c0f = pa[5 * HW + cell];
    const float c1f = pa[6 * HW + cell];
    const float c2f = pa[7 * HW + cell];
    const float m = fmaxf(fmaxf(c0f, c1f), c2f);
    const float e = fexp2((c0f - m) * LOG2E) + fexp2((c1f - m) * LOG2E)
                  + fexp2((c2f - m) * LOG2E);
    const float lse = m + flog2(e) * LN2;
    const int lab = P.labels[row + j];
    ce += lse - ((lab == 0) ? c0f : (lab == 1) ? c1f : c2f);
    const float4 bx = *(const float4*)(P.boxes + (size_t)(row + j) * 4);
    loc += sl1f(pa[0 * HW + cell] - bx.x) + sl1f(pa[1 * HW + cell] - bx.y)
         + sl1f(pa[2 * HW + cell] - bx.z) + sl1f(pa[3 * HW + cell] - bx.w);
  }

  // ---- packed block reduction of 9 scalars (one barrier round) ----
  {
    float v[9] = {nneg, posobj, ce, loc,
                  (float)lad0, (float)lad1, (float)lad2, (float)lad3,
                  (float)lad4};
    #pragma unroll
    for (int i = 0; i < 9; ++i) {
      #pragma unroll
      for (int off = 32; off > 0; off >>= 1) v[i] += __shfl_down(v[i], off);
    }
    const int lane = t & 63, w = t >> 6;
    __syncthreads();
    if (lane == 0) {
      #pragma unroll
      for (int i = 0; i < 9; ++i) S.wred[w][i] = v[i];
    }
    __syncthreads();
  }
  float red[9];
  #pragma unroll
  for (int i = 0; i < 9; ++i) {
    float acc = 0.f;
    #pragma unroll
    for (int w2 = 0; w2 < NWV; ++w2) acc += S.wred[w2][i];
    red[i] = acc;
  }
  const float t_po = red[1], t_ce = red[2], t_lc = red[3];
  const int k = min(3 * npos, (int)red[0]);

  float sel = 0.f;
  if (k > 0) {  // block-uniform
    // ---- pick prefilter rung: largest with count >= k (fallback: 0) ----
    unsigned Lkey = 0u;
    #pragma unroll
    for (int i = 0; i < 5; ++i)
      if ((int)red[4 + i] >= k) Lkey = LADDER[i];

    // ---- sweep A (LDS): sparse 2048-bin count hist above Lkey ----
    #pragma unroll
    for (int it = 0; it < ITER; ++it) {
      const int c8 = it * (BLK * 8) + t * 8;
      if (c8 < N) {
        const uint4 kv = *reinterpret_cast<const uint4*>(&S.keys[c8]);
        const unsigned ks[8] = {kv.x & 0xFFFFu, kv.x >> 16, kv.y & 0xFFFFu,
                                kv.y >> 16,     kv.z & 0xFFFFu, kv.z >> 16,
                                kv.w & 0xFFFFu, kv.w >> 16};
        #pragma unroll
        for (int q = 0; q < 8; ++q)
          if (ks[q] > Lkey) atomicAdd(&S.hc[ks[q] >> 5], 1u);   // ~3-7%
      }
    }
    __syncthreads();

    // ---- stage 1: 11-bit bins, counts only ----
    unsigned cb[4];
    #pragma unroll
    for (int q = 0; q < 4; ++q) cb[q] = S.hc[4 * t + q];
    selectBin1(cb, k, S.iwav, &S.sh_dig, &S.sh_krem);
    const int bin1 = S.sh_dig; const int krem1 = S.sh_krem;

    if (t < 32) { S.c32[t] = 0u; S.s32[t] = 0.f; }
    __syncthreads();

    // ---- sweep B (LDS): sum above bin1; 32-bin refine inside bin1 ----
    float sgt = 0.f;
    #pragma unroll
    for (int it = 0; it < ITER; ++it) {
      const int c8 = it * (BLK * 8) + t * 8;
      if (c8 < N) {
        const uint4 kv = *reinterpret_cast<const uint4*>(&S.keys[c8]);
        const unsigned ks[8] = {kv.x & 0xFFFFu, kv.x >> 16, kv.y & 0xFFFFu,
                                kv.y >> 16,     kv.z & 0xFFFFu, kv.z >> 16,
                                kv.w & 0xFFFFu, kv.w >> 16};
        #pragma unroll
        for (int q = 0; q < 8; ++q) {
          const unsigned k16 = ks[q];
          const int kb = (int)(k16 >> 5);
          if (kb > bin1) sgt += softplus_fast(recon16(k16));     // ~3%
          else if (kb == bin1 && k16 > Lkey) {   // same filter as hist
            atomicAdd(&S.c32[k16 & 31u], 1u);
            atomicAdd(&S.s32[k16 & 31u], softplus_fast(recon16(k16)));
          }
        }
      }
    }
    __syncthreads();
    const float t_sgt = blockSum(sgt, S.fscr);

    // ---- stage 2: 32 bins, one wave (lanes >=32 carry zeros) ----
    if (t < 64) {
      const int cc = (t < 32) ? (int)S.c32[t] : 0;
      const float ss = (t < 32) ? S.s32[t] : 0.f;
      int ci = cc; float si = ss;
      #pragma unroll
      for (int off = 1; off < 64; off <<= 1) {
        const int   co = __shfl_down(ci, off);
        const float so = __shfl_down(si, off);
        if ((t & 63) + off < 64) { ci += co; si += so; }
      }
      const int   above_c = ci - cc;     // count in bins strictly above t
      const float above_s = si - ss;
      if (t < 32 && cc > 0 && above_c < krem1 && krem1 <= above_c + cc) {
        S.sh_krem = krem1 - above_c;
        S.sh_sa   = t_sgt + above_s;
        S.sh_avg  = ss / (float)cc;      // tie-bin average (exact at key level)
      }
    }
    __syncthreads();
    sel = S.sh_sa + (float)S.sh_krem * S.sh_avg;
  }

  if (t == 0) {
    const float denom = (float)max(npos, 1);
    atomicAdd(&out[1], (t_po + sel) / denom);
    if (npos > 0) {
      atomicAdd(&out[2], t_ce / denom);
      atomicAdd(&out[3], t_lc / (denom * 4.f));
    }
    __threadfence();
    const unsigned old = atomicAdd(done, 1u);
    if (old == (unsigned)(R - 1)) {          // last row finalizes in place
      const float o = atomicAdd(&out[1], 0.f) * invB;
      const float c = atomicAdd(&out[2], 0.f) * invB;
      const float l = atomicAdd(&out[3], 0.f) * invB;
      out[0] = o + c + l;
      out[1] = o;
      out[2] = c;
      out[3] = l;
    }
  }
}

__global__ __launch_bounds__(BLK) void k_row(
    ScaleParams p0, ScaleParams p1, ScaleParams p2,
    int B, int R, float invB, float* out, unsigned* done) {
  __shared__ RowShared S;
  const int r = blockIdx.x;
  const int s = (r >= B) + (r >= 2 * B);   // heavy s0 rows dispatched first
  const int b = r - s * B;
  if (s == 0)      row_impl<19200>(p0, b, R, invB, out, done, S);
  else if (s == 1) row_impl<4800>(p1, b, R, invB, out, done, S);
  else             row_impl<1200>(p2, b, R, invB, out, done, S);
}

extern "C" void kernel_launch(void* const* d_in, const int* in_sizes, int n_in,
                              void* d_out, int out_size, void* d_ws, size_t ws_size,
                              hipStream_t stream) {
  (void)n_in; (void)out_size; (void)ws_size;

  const int HW0 = 80 * 80, HW1 = 40 * 40, HW2 = 20 * 20;
  const int B = in_sizes[0] / (NA * KCH * HW0);
  const int R = 3 * B;
  const float invB = 1.f / (float)B;

  ScaleParams p0{(const float*)d_in[0],  (const float*)d_in[1],
                 (const int*)d_in[2],    (const uint8_t*)d_in[3],
                 (const uint8_t*)d_in[4], HW0};
  ScaleParams p1{(const float*)d_in[5],  (const float*)d_in[6],
                 (const int*)d_in[7],    (const uint8_t*)d_in[8],
                 (const uint8_t*)d_in[9], HW1};
  ScaleParams p2{(const float*)d_in[10], (const float*)d_in[11],
                 (const int*)d_in[12],   (const uint8_t*)d_in[13],
                 (const uint8_t*)d_in[14], HW2};

  float* out = (float*)d_out;
  unsigned* done = (unsigned*)d_ws;

  k_zero<<<1, 64, 0, stream>>>(out, done);
  k_row<<<R, BLK, 0, stream>>>(p0, p1, p2, B, R, invB, out, done);
}

// Round 15
// 33.187 us; speedup vs baseline: 1.0516x; 1.0516x over previous
//
#include <hip/hip_runtime.h>
#include <stdint.h>

#define NA   3
#define KCH  8       // 5 + NUM_CLASSES
#define BLK  512
#define NWV  (BLK / 64)
#define NB   2048    // stage-1 bins: key16 >> 5 (sign+8exp+2mant)
#define MAXN 19200   // 3 * 80 * 80
#define QCAP 512
#define LKEY 0xBFA8u // key16 of softplus(1.0): hist prefilter rung (verified at runtime)

#define LOG2E 1.4426950408889634f
#define LN2   0.6931471805599453f

struct ScaleParams {
  const float*   pred;    // (B, 24, H, W)
  const float*   boxes;   // (B, N, 4)
  const int*     labels;  // (B, N)
  const uint8_t* pos;     // (B, N) bool
  const uint8_t* neg;     // (B, N) bool
  int HW;
};

__device__ __forceinline__ float fexp2(float x) { return __builtin_amdgcn_exp2f(x); }
__device__ __forceinline__ float flog2(float x) { return __builtin_amdgcn_logf(x); }

// logaddexp(0,x) = max(x,0) + log1p(exp(-|x|)); native exp2/log2, ~1e-6 rel
__device__ __forceinline__ float softplus_fast(float x) {
  const float t = fexp2(-fabsf(x) * LOG2E);
  return fmaxf(x, 0.f) + flog2(1.f + t) * LN2;
}

__device__ __forceinline__ float sl1f(float d) {
  float ad = fabsf(d);
  return (ad < 1.f) ? 0.5f * d * d : ad - 0.5f;
}

// order-preserving float->uint key (larger float => larger key)
__device__ __forceinline__ unsigned fkey(unsigned u) {
  return (u & 0x80000000u) ? ~u : (u | 0x80000000u);
}
__device__ __forceinline__ unsigned funkey(unsigned k) {
  return (k & 0x80000000u) ? (k & 0x7FFFFFFFu) : ~k;
}

// reconstruct approx value from 16-bit key (midpoint of the key interval)
__device__ __forceinline__ float recon16(unsigned k16) {
  return __uint_as_float(funkey((k16 << 16) | 0x8000u));
}

__device__ __forceinline__ float blockSum(float v, float* scr) {
  #pragma unroll
  for (int off = 32; off > 0; off >>= 1) v += __shfl_down(v, off);
  const int lane = threadIdx.x & 63, w = threadIdx.x >> 6;
  __syncthreads();                       // protect scr reuse
  if (lane == 0) scr[w] = v;
  __syncthreads();
  float r = 0.f;
  #pragma unroll
  for (int i = 0; i < NWV; ++i) r += scr[i];   // same-address broadcast
  return r;
}

// Stage-1 select: per-thread 4 consecutive bins (counts only) of ascending-key
// hist; find bin holding the krem-th LARGEST and remaining count inside it.
__device__ __forceinline__ void selectBin1(const unsigned* cb, int krem_in,
    int* iwav, int* sh_dig, int* sh_krem) {
  const int t = threadIdx.x, lane = t & 63, w = t >> 6;
  const int c_t = (int)(cb[0] + cb[1] + cb[2] + cb[3]);
  int ci = c_t;                          // wave inclusive suffix scan
  #pragma unroll
  for (int off = 1; off < 64; off <<= 1) {
    const int co = __shfl_down(ci, off);
    if (lane + off < 64) ci += co;
  }
  __syncthreads();                       // protect iwav reuse
  if (lane == 0) iwav[w] = ci;
  __syncthreads();
  int ac = 0;
  #pragma unroll
  for (int w2 = 0; w2 < NWV; ++w2) if (w2 > w) ac += iwav[w2];
  int cum_c = (ci - c_t) + ac;           // count strictly above thread's top bin
  #pragma unroll
  for (int q = 3; q >= 0; --q) {
    const int cq = (int)cb[q];
    if (cq > 0 && cum_c < krem_in && krem_in <= cum_c + cq) {  // unique bracket
      *sh_dig  = t * 4 + q;
      *sh_krem = krem_in - cum_c;
    }
    cum_c += cq;
  }
  __syncthreads();
}

__global__ void k_zero(float* out, unsigned* done) {
  if (threadIdx.x < 4) out[threadIdx.x] = 0.f;
  if (threadIdx.x == 0) *done = 0u;
}

struct RowShared {
  unsigned short keys[MAXN];   // 38.4 KB (0 = not-neg; sp keys are >= 0x8000)
  unsigned hc[NB];             // 8 KB
  int      queue[QCAP];
  int      sh_qn;
  int      iwav[NWV];
  float    fscr[NWV];
  float    wred[NWV][5];       // packed block-reduction scratch
  int      sh_dig, sh_krem;
  float    sh_sa, sh_avg;
  unsigned c32[32];
  float    s32[32];
};

// Whole-row processing, compile-time N. Round-12 structure + rung prefilter:
// phase B histograms only keys > LKEY (~16% of negs) — runtime-verified,
// exact fallback completes the histogram if count(>LKEY) < k.
template<int N>
__device__ __forceinline__ void row_impl(
    const ScaleParams P, int b, int R, float invB,
    float* out, unsigned* done, RowShared& S) {
  constexpr int HW = N / 3;
  constexpr int ITER = (N + BLK * 8 - 1) / (BLK * 8);
  const int t = threadIdx.x;

  for (int i = t; i < NB; i += BLK) S.hc[i] = 0u;
  if (t == 0) S.sh_qn = 0;
  __syncthreads();

  const float* predb = P.pred + (size_t)b * (NA * KCH) * HW;
  const size_t row = (size_t)b * N;
  float nneg = 0.f;
  int above = 0;

  // ---- sweep 1, phase A: issue ALL global loads (compile-time unroll) ----
  float4 o0[ITER], o1[ITER];
  uint2  pmv[ITER], nmv[ITER];
  #pragma unroll
  for (int it = 0; it < ITER; ++it) {
    const int c8 = it * (BLK * 8) + t * 8;
    if (c8 < N) {
      const int a = (c8 >= HW) + (c8 >= 2 * HW);
      const int cell = c8 - a * HW;
      const float* po = predb + (size_t)a * KCH * HW + 4 * HW + cell;
      o0[it]  = *(const float4*)po;
      o1[it]  = *(const float4*)(po + 4);
      pmv[it] = *(const uint2*)(P.pos + row + c8);
      nmv[it] = *(const uint2*)(P.neg + row + c8);
    }
  }

  // ---- sweep 1, phase B: keys -> LDS, filtered count hist, pos queue ----
  #pragma unroll
  for (int it = 0; it < ITER; ++it) {
    const int c8 = it * (BLK * 8) + t * 8;
    if (c8 < N) {
      const unsigned long long nm64 =
          ((unsigned long long)nmv[it].y << 32) | nmv[it].x;
      nneg += (float)__popcll(nm64);       // bool bytes are 0/1
      unsigned kk[8];
      #pragma unroll
      for (int q = 0; q < 8; ++q) {
        const float obj = (q < 4) ? (&o0[it].x)[q] : (&o1[it].x)[q - 4];
        const unsigned nm = ((q < 4) ? (nmv[it].x >> (8 * q))
                                     : (nmv[it].y >> (8 * (q - 4)))) & 0xFFu;
        const unsigned pm = ((q < 4) ? (pmv[it].x >> (8 * q))
                                     : (pmv[it].y >> (8 * (q - 4)))) & 0xFFu;
        unsigned k16 = 0u;
        if (nm) {
          k16 = fkey(__float_as_uint(obj)) >> 16;   // sp>=0 => k16>=0x8000, never 0
          if (k16 > LKEY) {                // prefilter: ~16% do atomics
            ++above;
            atomicAdd(&S.hc[k16 >> 5], 1u);
          }
        }
        kk[q] = k16;
        if (pm) {
          const int idx = atomicAdd(&S.sh_qn, 1);
          if (idx < QCAP) S.queue[idx] = c8 + q;
        }
      }
      uint4 kv;
      kv.x = kk[0] | (kk[1] << 16); kv.y = kk[2] | (kk[3] << 16);
      kv.z = kk[4] | (kk[5] << 16); kv.w = kk[6] | (kk[7] << 16);
      *reinterpret_cast<uint4*>(&S.keys[c8]) = kv;
    }
  }
  __syncthreads();
  const int npos = S.sh_qn;
  const int qn = min(npos, QCAP);

  // ---- dense pos-anchor work (~1%): softplus/CE/smooth-L1, L2-hot ----
  float posobj = 0.f, ce = 0.f, loc = 0.f;
  for (int i = t; i < qn; i += BLK) {
    const int j = S.queue[i];
    const int a = (j >= HW) + (j >= 2 * HW);
    const int cell = j - a * HW;
    const float* pa = predb + (size_t)a * KCH * HW;
    posobj += softplus_fast(-pa[4 * HW + cell]);     // sp(x)-x == sp(-x)
    const float c0f = pa[5 * HW + cell];
    const float c1f = pa[6 * HW + cell];
    const float c2f = pa[7 * HW + cell];
    const float m = fmaxf(fmaxf(c0f, c1f), c2f);
    const float e = fexp2((c0f - m) * LOG2E) + fexp2((c1f - m) * LOG2E)
                  + fexp2((c2f - m) * LOG2E);
    const float lse = m + flog2(e) * LN2;
    const int lab = P.labels[row + j];
    ce += lse - ((lab == 0) ? c0f : (lab == 1) ? c1f : c2f);
    const float4 bx = *(const float4*)(P.boxes + (size_t)(row + j) * 4);
    loc += sl1f(pa[0 * HW + cell] - bx.x) + sl1f(pa[1 * HW + cell] - bx.y)
         + sl1f(pa[2 * HW + cell] - bx.z) + sl1f(pa[3 * HW + cell] - bx.w);
  }

  // ---- packed block reduction of 5 scalars (one barrier round) ----
  {
    float v[5] = {nneg, posobj, ce, loc, (float)above};
    #pragma unroll
    for (int i = 0; i < 5; ++i) {
      #pragma unroll
      for (int off = 32; off > 0; off >>= 1) v[i] += __shfl_down(v[i], off);
    }
    const int lane = t & 63, w = t >> 6;
    __syncthreads();
    if (lane == 0) {
      #pragma unroll
      for (int i = 0; i < 5; ++i) S.wred[w][i] = v[i];
    }
    __syncthreads();
  }
  float red[5];
  #pragma unroll
  for (int i = 0; i < 5; ++i) {
    float acc = 0.f;
    #pragma unroll
    for (int w2 = 0; w2 < NWV; ++w2) acc += S.wred[w2][i];
    red[i] = acc;
  }
  const float t_po = red[1], t_ce = red[2], t_lc = red[3];
  const int t_above = (int)red[4];
  const int k = min(3 * npos, (int)red[0]);

  float sel = 0.f;
  if (k > 0) {  // block-uniform
    unsigned Lcur = LKEY;
    if (t_above < k) {
      // rare exact fallback: complete the histogram for keys <= LKEY
      #pragma unroll
      for (int it = 0; it < ITER; ++it) {
        const int c8 = it * (BLK * 8) + t * 8;
        if (c8 < N) {
          const uint4 kv = *reinterpret_cast<const uint4*>(&S.keys[c8]);
          const unsigned ks[8] = {kv.x & 0xFFFFu, kv.x >> 16, kv.y & 0xFFFFu,
                                  kv.y >> 16,     kv.z & 0xFFFFu, kv.z >> 16,
                                  kv.w & 0xFFFFu, kv.w >> 16};
          #pragma unroll
          for (int q = 0; q < 8; ++q)
            if (ks[q] && ks[q] <= LKEY) atomicAdd(&S.hc[ks[q] >> 5], 1u);
        }
      }
      __syncthreads();
      Lcur = 0u;
    }

    // ---- stage 1: 11-bit bins, counts only ----
    unsigned cb[4];
    #pragma unroll
    for (int q = 0; q < 4; ++q) cb[q] = S.hc[4 * t + q];
    selectBin1(cb, k, S.iwav, &S.sh_dig, &S.sh_krem);
    const int bin1 = S.sh_dig; const int krem1 = S.sh_krem;

    if (t < 32) { S.c32[t] = 0u; S.s32[t] = 0.f; }
    __syncthreads();

    // ---- sweep 2 (LDS only): sum above bin1; 32-bin refine inside bin1 ----
    float sgt = 0.f;
    #pragma unroll
    for (int it = 0; it < ITER; ++it) {
      const int c8 = it * (BLK * 8) + t * 8;
      if (c8 < N) {
        const uint4 kv = *reinterpret_cast<const uint4*>(&S.keys[c8]);
        const unsigned ks[8] = {kv.x & 0xFFFFu, kv.x >> 16, kv.y & 0xFFFFu,
                                kv.y >> 16,     kv.z & 0xFFFFu, kv.z >> 16,
                                kv.w & 0xFFFFu, kv.w >> 16};
        #pragma unroll
        for (int q = 0; q < 8; ++q) {
          const unsigned k16 = ks[q];
          if (!k16) continue;
          const int kb = (int)(k16 >> 5);
          if (kb > bin1) sgt += softplus_fast(recon16(k16));     // ~3%
          else if (kb == bin1 && k16 > Lcur) {  // match bracket's counts
            atomicAdd(&S.c32[k16 & 31u], 1u);
            atomicAdd(&S.s32[k16 & 31u], softplus_fast(recon16(k16)));
          }
        }
      }
    }
    __syncthreads();
    const float t_sgt = blockSum(sgt, S.fscr);

    // ---- stage 2: 32 bins, one wave (lanes >=32 carry zeros) ----
    if (t < 64) {
      const int cc = (t < 32) ? (int)S.c32[t] : 0;
      const float ss = (t < 32) ? S.s32[t] : 0.f;
      int ci = cc; float si = ss;
      #pragma unroll
      for (int off = 1; off < 64; off <<= 1) {
        const int   co = __shfl_down(ci, off);
        const float so = __shfl_down(si, off);
        if ((t & 63) + off < 64) { ci += co; si += so; }
      }
      const int   above_c = ci - cc;     // count in bins strictly above t
      const float above_s = si - ss;
      if (t < 32 && cc > 0 && above_c < krem1 && krem1 <= above_c + cc) {
        S.sh_krem = krem1 - above_c;
        S.sh_sa   = t_sgt + above_s;
        S.sh_avg  = ss / (float)cc;      // tie-bin average (exact at key level)
      }
    }
    __syncthreads();
    sel = S.sh_sa + (float)S.sh_krem * S.sh_avg;
  }

  if (t == 0) {
    const float denom = (float)max(npos, 1);
    atomicAdd(&out[1], (t_po + sel) / denom);
    if (npos > 0) {
      atomicAdd(&out[2], t_ce / denom);
      atomicAdd(&out[3], t_lc / (denom * 4.f));
    }
    __threadfence();
    const unsigned old = atomicAdd(done, 1u);
    if (old == (unsigned)(R - 1)) {          // last row finalizes in place
      const float o = atomicAdd(&out[1], 0.f) * invB;
      const float c = atomicAdd(&out[2], 0.f) * invB;
      const float l = atomicAdd(&out[3], 0.f) * invB;
      out[0] = o + c + l;
      out[1] = o;
      out[2] = c;
      out[3] = l;
    }
  }
}

__global__ __launch_bounds__(BLK) void k_row(
    ScaleParams p0, ScaleParams p1, ScaleParams p2,
    int B, int R, float invB, float* out, unsigned* done) {
  __shared__ RowShared S;
  const int r = blockIdx.x;
  const int s = (r >= B) + (r >= 2 * B);   // heavy s0 rows dispatched first
  const int b = r - s * B;
  if (s == 0)      row_impl<19200>(p0, b, R, invB, out, done, S);
  else if (s == 1) row_impl<4800>(p1, b, R, invB, out, done, S);
  else             row_impl<1200>(p2, b, R, invB, out, done, S);
}

extern "C" void kernel_launch(void* const* d_in, const int* in_sizes, int n_in,
                              void* d_out, int out_size, void* d_ws, size_t ws_size,
                              hipStream_t stream) {
  (void)n_in; (void)out_size; (void)ws_size;

  const int HW0 = 80 * 80, HW1 = 40 * 40, HW2 = 20 * 20;
  const int B = in_sizes[0] / (NA * KCH * HW0);
  const int R = 3 * B;
  const float invB = 1.f / (float)B;

  ScaleParams p0{(const float*)d_in[0],  (const float*)d_in[1],
                 (const int*)d_in[2],    (const uint8_t*)d_in[3],
                 (const uint8_t*)d_in[4], HW0};
  ScaleParams p1{(const float*)d_in[5],  (const float*)d_in[6],
                 (const int*)d_in[7],    (const uint8_t*)d_in[8],
                 (const uint8_t*)d_in[9], HW1};
  ScaleParams p2{(const float*)d_in[10], (const float*)d_in[11],
                 (const int*)d_in[12],   (const uint8_t*)d_in[13],
                 (const uint8_t*)d_in[14], HW2};

  float* out = (float*)d_out;
  unsigned* done = (unsigned*)d_ws;

  k_zero<<<1, 64, 0, stream>>>(out, done);
  k_row<<<R, BLK, 0, stream>>>(p0, p1, p2, B, R, invB, out, done);
}

// Round 16
// 26.721 us; speedup vs baseline: 1.3061x; 1.2420x over previous
//
#include <hip/hip_runtime.h>
#include <stdint.h>

#define NA   3
#define KCH  8       // 5 + NUM_CLASSES
#define BLK  512
#define NWV  (BLK / 64)
#define NB   2048    // stage-1 bins: key16 >> 5 (sign+8exp+2mant)
#define MAXN 19200   // 3 * 80 * 80
#define QCAP 512
#define LKEY 0xBFA8u // key16 of softplus(1.0): hist prefilter rung (verified at runtime)

#define LOG2E 1.4426950408889634f
#define LN2   0.6931471805599453f

struct ScaleParams {
  const float*   pred;    // (B, 24, H, W)
  const float*   boxes;   // (B, N, 4)
  const int*     labels;  // (B, N)
  const uint8_t* pos;     // (B, N) bool
  const uint8_t* neg;     // (B, N) bool
  int HW;
};

__device__ __forceinline__ float fexp2(float x) { return __builtin_amdgcn_exp2f(x); }
__device__ __forceinline__ float flog2(float x) { return __builtin_amdgcn_logf(x); }

// logaddexp(0,x) = max(x,0) + log1p(exp(-|x|)); native exp2/log2, ~1e-6 rel
__device__ __forceinline__ float softplus_fast(float x) {
  const float t = fexp2(-fabsf(x) * LOG2E);
  return fmaxf(x, 0.f) + flog2(1.f + t) * LN2;
}

__device__ __forceinline__ float sl1f(float d) {
  float ad = fabsf(d);
  return (ad < 1.f) ? 0.5f * d * d : ad - 0.5f;
}

// order-preserving float->uint key (larger float => larger key)
__device__ __forceinline__ unsigned fkey(unsigned u) {
  return (u & 0x80000000u) ? ~u : (u | 0x80000000u);
}
__device__ __forceinline__ unsigned funkey(unsigned k) {
  return (k & 0x80000000u) ? (k & 0x7FFFFFFFu) : ~k;
}

// reconstruct approx value from 16-bit key (midpoint of the key interval)
__device__ __forceinline__ float recon16(unsigned k16) {
  return __uint_as_float(funkey((k16 << 16) | 0x8000u));
}

__device__ __forceinline__ float blockSum(float v, float* scr) {
  #pragma unroll
  for (int off = 32; off > 0; off >>= 1) v += __shfl_down(v, off);
  const int lane = threadIdx.x & 63, w = threadIdx.x >> 6;
  __syncthreads();                       // protect scr reuse
  if (lane == 0) scr[w] = v;
  __syncthreads();
  float r = 0.f;
  #pragma unroll
  for (int i = 0; i < NWV; ++i) r += scr[i];   // same-address broadcast
  return r;
}

// Stage-1 select: per-thread 4 consecutive bins (counts only) of ascending-key
// hist; find bin holding the krem-th LARGEST and remaining count inside it.
__device__ __forceinline__ void selectBin1(const unsigned* cb, int krem_in,
    int* iwav, int* sh_dig, int* sh_krem) {
  const int t = threadIdx.x, lane = t & 63, w = t >> 6;
  const int c_t = (int)(cb[0] + cb[1] + cb[2] + cb[3]);
  int ci = c_t;                          // wave inclusive suffix scan
  #pragma unroll
  for (int off = 1; off < 64; off <<= 1) {
    const int co = __shfl_down(ci, off);
    if (lane + off < 64) ci += co;
  }
  __syncthreads();                       // protect iwav reuse
  if (lane == 0) iwav[w] = ci;
  __syncthreads();
  int ac = 0;
  #pragma unroll
  for (int w2 = 0; w2 < NWV; ++w2) if (w2 > w) ac += iwav[w2];
  int cum_c = (ci - c_t) + ac;           // count strictly above thread's top bin
  #pragma unroll
  for (int q = 3; q >= 0; --q) {
    const int cq = (int)cb[q];
    if (cq > 0 && cum_c < krem_in && krem_in <= cum_c + cq) {  // unique bracket
      *sh_dig  = t * 4 + q;
      *sh_krem = krem_in - cum_c;
    }
    cum_c += cq;
  }
  __syncthreads();
}

__global__ void k_zero(unsigned* done) {
  if (threadIdx.x == 0) *done = 0u;
}

struct RowShared {
  unsigned short keys[MAXN];   // 38.4 KB (0 = not-neg; sp keys are >= 0x8000)
  unsigned hc[NB];             // 8 KB
  int      queue[QCAP];
  int      sh_qn;
  int      iwav[NWV];
  float    fscr[NWV];
  float    wred[NWV][5];       // packed block-reduction scratch
  int      sh_dig, sh_krem;
  float    sh_sa, sh_avg;
  int      sh_flag;
  unsigned c32[32];
  float    s32[32];
};

// Whole-row processing, compile-time N (identical to round 15). Emits the
// row's (obj, cls, loc) triple via PLAIN STORES to part[0..2] — no atomics.
template<int N>
__device__ __forceinline__ void row_impl(
    const ScaleParams P, int b, float* part, RowShared& S) {
  constexpr int HW = N / 3;
  constexpr int ITER = (N + BLK * 8 - 1) / (BLK * 8);
  const int t = threadIdx.x;

  for (int i = t; i < NB; i += BLK) S.hc[i] = 0u;
  if (t == 0) S.sh_qn = 0;
  __syncthreads();

  const float* predb = P.pred + (size_t)b * (NA * KCH) * HW;
  const size_t row = (size_t)b * N;
  float nneg = 0.f;
  int above = 0;

  // ---- sweep 1, phase A: issue ALL global loads (compile-time unroll) ----
  float4 o0[ITER], o1[ITER];
  uint2  pmv[ITER], nmv[ITER];
  #pragma unroll
  for (int it = 0; it < ITER; ++it) {
    const int c8 = it * (BLK * 8) + t * 8;
    if (c8 < N) {
      const int a = (c8 >= HW) + (c8 >= 2 * HW);
      const int cell = c8 - a * HW;
      const float* po = predb + (size_t)a * KCH * HW + 4 * HW + cell;
      o0[it]  = *(const float4*)po;
      o1[it]  = *(const float4*)(po + 4);
      pmv[it] = *(const uint2*)(P.pos + row + c8);
      nmv[it] = *(const uint2*)(P.neg + row + c8);
    }
  }

  // ---- sweep 1, phase B: keys -> LDS, filtered count hist, pos queue ----
  #pragma unroll
  for (int it = 0; it < ITER; ++it) {
    const int c8 = it * (BLK * 8) + t * 8;
    if (c8 < N) {
      const unsigned long long nm64 =
          ((unsigned long long)nmv[it].y << 32) | nmv[it].x;
      nneg += (float)__popcll(nm64);       // bool bytes are 0/1
      unsigned kk[8];
      #pragma unroll
      for (int q = 0; q < 8; ++q) {
        const float obj = (q < 4) ? (&o0[it].x)[q] : (&o1[it].x)[q - 4];
        const unsigned nm = ((q < 4) ? (nmv[it].x >> (8 * q))
                                     : (nmv[it].y >> (8 * (q - 4)))) & 0xFFu;
        const unsigned pm = ((q < 4) ? (pmv[it].x >> (8 * q))
                                     : (pmv[it].y >> (8 * (q - 4)))) & 0xFFu;
        unsigned k16 = 0u;
        if (nm) {
          k16 = fkey(__float_as_uint(obj)) >> 16;   // sp>=0 => k16>=0x8000, never 0
          if (k16 > LKEY) {                // prefilter: ~16% do atomics
            ++above;
            atomicAdd(&S.hc[k16 >> 5], 1u);
          }
        }
        kk[q] = k16;
        if (pm) {
          const int idx = atomicAdd(&S.sh_qn, 1);
          if (idx < QCAP) S.queue[idx] = c8 + q;
        }
      }
      uint4 kv;
      kv.x = kk[0] | (kk[1] << 16); kv.y = kk[2] | (kk[3] << 16);
      kv.z = kk[4] | (kk[5] << 16); kv.w = kk[6] | (kk[7] << 16);
      *reinterpret_cast<uint4*>(&S.keys[c8]) = kv;
    }
  }
  __syncthreads();
  const int npos = S.sh_qn;
  const int qn = min(npos, QCAP);

  // ---- dense pos-anchor work (~1%): softplus/CE/smooth-L1, L2-hot ----
  float posobj = 0.f, ce = 0.f, loc = 0.f;
  for (int i = t; i < qn; i += BLK) {
    const int j = S.queue[i];
    const int a = (j >= HW) + (j >= 2 * HW);
    const int cell = j - a * HW;
    const float* pa = predb + (size_t)a * KCH * HW;
    posobj += softplus_fast(-pa[4 * HW + cell]);     // sp(x)-x == sp(-x)
    const float c0f = pa[5 * HW + cell];
    const float c1f = pa[6 * HW + cell];
    const float c2f = pa[7 * HW + cell];
    const float m = fmaxf(fmaxf(c0f, c1f), c2f);
    const float e = fexp2((c0f - m) * LOG2E) + fexp2((c1f - m) * LOG2E)
                  + fexp2((c2f - m) * LOG2E);
    const float lse = m + flog2(e) * LN2;
    const int lab = P.labels[row + j];
    ce += lse - ((lab == 0) ? c0f : (lab == 1) ? c1f : c2f);
    const float4 bx = *(const float4*)(P.boxes + (size_t)(row + j) * 4);
    loc += sl1f(pa[0 * HW + cell] - bx.x) + sl1f(pa[1 * HW + cell] - bx.y)
         + sl1f(pa[2 * HW + cell] - bx.z) + sl1f(pa[3 * HW + cell] - bx.w);
  }

  // ---- packed block reduction of 5 scalars (one barrier round) ----
  {
    float v[5] = {nneg, posobj, ce, loc, (float)above};
    #pragma unroll
    for (int i = 0; i < 5; ++i) {
      #pragma unroll
      for (int off = 32; off > 0; off >>= 1) v[i] += __shfl_down(v[i], off);
    }
    const int lane = t & 63, w = t >> 6;
    __syncthreads();
    if (lane == 0) {
      #pragma unroll
      for (int i = 0; i < 5; ++i) S.wred[w][i] = v[i];
    }
    __syncthreads();
  }
  float red[5];
  #pragma unroll
  for (int i = 0; i < 5; ++i) {
    float acc = 0.f;
    #pragma unroll
    for (int w2 = 0; w2 < NWV; ++w2) acc += S.wred[w2][i];
    red[i] = acc;
  }
  const float t_po = red[1], t_ce = red[2], t_lc = red[3];
  const int t_above = (int)red[4];
  const int k = min(3 * npos, (int)red[0]);

  float sel = 0.f;
  if (k > 0) {  // block-uniform
    unsigned Lcur = LKEY;
    if (t_above < k) {
      // rare exact fallback: complete the histogram for keys <= LKEY
      #pragma unroll
      for (int it = 0; it < ITER; ++it) {
        const int c8 = it * (BLK * 8) + t * 8;
        if (c8 < N) {
          const uint4 kv = *reinterpret_cast<const uint4*>(&S.keys[c8]);
          const unsigned ks[8] = {kv.x & 0xFFFFu, kv.x >> 16, kv.y & 0xFFFFu,
                                  kv.y >> 16,     kv.z & 0xFFFFu, kv.z >> 16,
                                  kv.w & 0xFFFFu, kv.w >> 16};
          #pragma unroll
          for (int q = 0; q < 8; ++q)
            if (ks[q] && ks[q] <= LKEY) atomicAdd(&S.hc[ks[q] >> 5], 1u);
        }
      }
      __syncthreads();
      Lcur = 0u;
    }

    // ---- stage 1: 11-bit bins, counts only ----
    unsigned cb[4];
    #pragma unroll
    for (int q = 0; q < 4; ++q) cb[q] = S.hc[4 * t + q];
    selectBin1(cb, k, S.iwav, &S.sh_dig, &S.sh_krem);
    const int bin1 = S.sh_dig; const int krem1 = S.sh_krem;

    if (t < 32) { S.c32[t] = 0u; S.s32[t] = 0.f; }
    __syncthreads();

    // ---- sweep 2 (LDS only): sum above bin1; 32-bin refine inside bin1 ----
    float sgt = 0.f;
    #pragma unroll
    for (int it = 0; it < ITER; ++it) {
      const int c8 = it * (BLK * 8) + t * 8;
      if (c8 < N) {
        const uint4 kv = *reinterpret_cast<const uint4*>(&S.keys[c8]);
        const unsigned ks[8] = {kv.x & 0xFFFFu, kv.x >> 16, kv.y & 0xFFFFu,
                                kv.y >> 16,     kv.z & 0xFFFFu, kv.z >> 16,
                                kv.w & 0xFFFFu, kv.w >> 16};
        #pragma unroll
        for (int q = 0; q < 8; ++q) {
          const unsigned k16 = ks[q];
          if (!k16) continue;
          const int kb = (int)(k16 >> 5);
          if (kb > bin1) sgt += softplus_fast(recon16(k16));     // ~3%
          else if (kb == bin1 && k16 > Lcur) {  // match bracket's counts
            atomicAdd(&S.c32[k16 & 31u], 1u);
            atomicAdd(&S.s32[k16 & 31u], softplus_fast(recon16(k16)));
          }
        }
      }
    }
    __syncthreads();
    const float t_sgt = blockSum(sgt, S.fscr);

    // ---- stage 2: 32 bins, one wave (lanes >=32 carry zeros) ----
    if (t < 64) {
      const int cc = (t < 32) ? (int)S.c32[t] : 0;
      const float ss = (t < 32) ? S.s32[t] : 0.f;
      int ci = cc; float si = ss;
      #pragma unroll
      for (int off = 1; off < 64; off <<= 1) {
        const int   co = __shfl_down(ci, off);
        const float so = __shfl_down(si, off);
        if ((t & 63) + off < 64) { ci += co; si += so; }
      }
      const int   above_c = ci - cc;     // count in bins strictly above t
      const float above_s = si - ss;
      if (t < 32 && cc > 0 && above_c < krem1 && krem1 <= above_c + cc) {
        S.sh_krem = krem1 - above_c;
        S.sh_sa   = t_sgt + above_s;
        S.sh_avg  = ss / (float)cc;      // tie-bin average (exact at key level)
      }
    }
    __syncthreads();
    sel = S.sh_sa + (float)S.sh_krem * S.sh_avg;
  }

  if (t == 0) {
    const float denom = (float)max(npos, 1);
    part[0] = (t_po + sel) / denom;                       // plain stores:
    part[1] = (npos > 0) ? t_ce / denom : 0.f;            // distinct addresses,
    part[2] = (npos > 0) ? t_lc / (denom * 4.f) : 0.f;    // no RMW contention
  }
}

// One block per (scale, batch) row; last-arriving block reduces g_part -> out.
__global__ __launch_bounds__(BLK) void k_row(
    ScaleParams p0, ScaleParams p1, ScaleParams p2,
    int B, int R, float invB, float* g_part, unsigned* done, float* out) {
  __shared__ RowShared S;
  const int r = blockIdx.x;
  const int s = (r >= B) + (r >= 2 * B);   // heavy s0 rows dispatched first
  const int b = r - s * B;
  float* part = g_part + (size_t)r * 4;
  if (s == 0)      row_impl<19200>(p0, b, part, S);
  else if (s == 1) row_impl<4800>(p1, b, part, S);
  else             row_impl<1200>(p2, b, part, S);

  if (threadIdx.x == 0) {
    __threadfence();                          // release part[] stores
    const unsigned old = atomicAdd(done, 1u); // single-word ticket
    S.sh_flag = (old == (unsigned)(R - 1)) ? 1 : 0;
  }
  __syncthreads();
  if (S.sh_flag) {
    __threadfence();                          // acquire side
    const int t = threadIdx.x;
    float o = 0.f, c = 0.f, l = 0.f;
    for (int i = t; i < R; i += BLK) {
      o += g_part[i * 4 + 0];
      c += g_part[i * 4 + 1];
      l += g_part[i * 4 + 2];
    }
    o = blockSum(o, S.fscr);
    c = blockSum(c, S.fscr);
    l = blockSum(l, S.fscr);
    if (t == 0) {
      out[0] = (o + c + l) * invB;
      out[1] = o * invB;
      out[2] = c * invB;
      out[3] = l * invB;
    }
  }
}

extern "C" void kernel_launch(void* const* d_in, const int* in_sizes, int n_in,
                              void* d_out, int out_size, void* d_ws, size_t ws_size,
                              hipStream_t stream) {
  (void)n_in; (void)out_size; (void)ws_size;

  const int HW0 = 80 * 80, HW1 = 40 * 40, HW2 = 20 * 20;
  const int B = in_sizes[0] / (NA * KCH * HW0);
  const int R = 3 * B;
  const float invB = 1.f / (float)B;

  ScaleParams p0{(const float*)d_in[0],  (const float*)d_in[1],
                 (const int*)d_in[2],    (const uint8_t*)d_in[3],
                 (const uint8_t*)d_in[4], HW0};
  ScaleParams p1{(const float*)d_in[5],  (const float*)d_in[6],
                 (const int*)d_in[7],    (const uint8_t*)d_in[8],
                 (const uint8_t*)d_in[9], HW1};
  ScaleParams p2{(const float*)d_in[10], (const float*)d_in[11],
                 (const int*)d_in[12],   (const uint8_t*)d_in[13],
                 (const uint8_t*)d_in[14], HW2};

  float* out = (float*)d_out;
  unsigned* done = (unsigned*)d_ws;
  float* g_part = (float*)((char*)d_ws + 256);   // R*4 floats, plain stores

  k_zero<<<1, 64, 0, stream>>>(done);
  k_row<<<R, BLK, 0, stream>>>(p0, p1, p2, B, R, invB, g_part, done, out);
}